// Round 4
// baseline (14463.107 us; speedup 1.0000x reference)
//
#include <hip/hip_runtime.h>
#include <hip/hip_bf16.h>
#include <cmath>

// L=128, B=256, H=256, C=17, Y=16, N_SUB=2
#define L_   128
#define B_   256
#define H_   256
#define C_   17
#define Y_   16
#define NSUB 254
#define NBLK 256

typedef short bf16x8 __attribute__((ext_vector_type(8)));
typedef float f32x4  __attribute__((ext_vector_type(4)));

// ---- workspace byte offsets -------------------------------------------------
// dXr  [254][256 b][20 c-pad] f32                     5,201,920
// zP   [2 ping-pong][4 bq][64 h4][64 b][4 kk] f32       524,288
// hdnG hi/lo planes, frag-ordered bf16, per bq 16384     131,072 each
// W2F  hi/lo planes, frag-ordered bf16                 5,242,880 each
// barrier: cnt @ +0, gen @ +128
#define OFF_DXR  0u
#define OFF_ZP   5201920u
#define OFF_HHI  5726208u
#define OFF_HLO  5857280u
#define OFF_W2H  5988352u
#define OFF_W2L  11231232u
#define OFF_BAR  16474112u

__device__ __forceinline__ float fast_tanh(float x) {
  float e = __expf(2.0f * x);
  return 1.0f - __fdividef(2.0f, e + 1.0f);
}

__device__ __forceinline__ void bsplit(float x, unsigned short& hi, unsigned short& lo) {
  __hip_bfloat16 h = __float2bfloat16(x);
  float hf = __bfloat162float(h);
  __hip_bfloat16 l = __float2bfloat16(x - hf);
  hi = *(unsigned short*)&h;
  lo = *(unsigned short*)&l;
}

// ---------------------------------------------------------------------------
// dXr[sub][b][c(20 pad)] = dX * (h/2)   (c>=17 -> 0)
__global__ void k_dx(const float* __restrict__ ts, const float* __restrict__ us,
                     float* __restrict__ dXr) {
  int idx = blockIdx.x * 256 + threadIdx.x;     // 254*256*20 = 1,300,480 exact
  int c   = idx % 20;
  int t2  = idx / 20;
  int b   = t2 & 255;
  int sub = t2 >> 8;
  if (c >= C_) { dXr[idx] = 0.f; return; }
  int s = sub >> 1, j = sub & 1;
  float t_s = ts[s * B_], t_n = ts[(s + 1) * B_];
  float h = t_n - t_s;
  float xi, xn;
  if (c == 0) { xi = ts[s * B_ + b]; xn = ts[(s + 1) * B_ + b]; }
  else {
    xi = us[(size_t)s       * 4096 + b * 16 + (c - 1)];
    xn = us[(size_t)(s + 1) * 4096 + b * 16 + (c - 1)];
  }
  float mn = (xn - xi) / h;
  float mi;
  if (s == 0) mi = mn;
  else {
    float hp = t_s - ts[(s - 1) * B_];
    float xp = (c == 0) ? ts[(s - 1) * B_ + b]
                        : us[(size_t)(s - 1) * 4096 + b * 16 + (c - 1)];
    mi = (xi - xp) / hp;
  }
  float c2 = 3.f * (xn - xi) / (h * h) - (2.f * mi + mn) / h;
  float c3 = 2.f * (xi - xn) / (h * h * h) + (mi + mn) / (h * h);
  float u  = j ? 0.5f * h : 0.f;
  float dX = mi + 2.f * c2 * u + 3.f * c3 * u * u;
  dXr[idx] = dX * 0.5f * h;
}

// ---------------------------------------------------------------------------
// Build W2 A-fragments (transposed GEMM: A[m=col(80)][k=256]), hi/lo bf16.
// A-frag layout assumption: lane l: m = mt*16+(l&15); elem e: k = kq*64+kt*32
//   + 4*(l>>4) + (e&3) + 16*(e>>2).   [flip-plan: k = (l>>4)*8 + e]
__global__ void k_w2f(const float* __restrict__ W2,
                      unsigned short* __restrict__ W2H,
                      unsigned short* __restrict__ W2L) {
  int idx = blockIdx.x * 256 + threadIdx.x;     // 2,621,440 exact
  int e = idx & 7, t = idx >> 3;
  int lane = t & 63; t >>= 6;
  int mt = t % 5;  t /= 5;
  int kt = t & 1;  t >>= 1;
  int kq = t & 3;  t >>= 2;
  int hq = t;                                   // 0..63
  int col = mt * 16 + (lane & 15);
  int hl = col / 20, c = col - hl * 20;
  int k = kq * 64 + kt * 32 + 4 * (lane >> 4) + (e & 3) + 16 * (e >> 2);
  float v = (c < C_) ? W2[(size_t)k * (H_ * C_) + (hq * 4 + hl) * C_ + c] : 0.f;
  unsigned short hi, lo;
  bsplit(v, hi, lo);
  W2H[idx] = hi;
  W2L[idx] = lo;
}

// zP buf0 init: layout [bq][h4][b64][kk], z0[b][h] = enc_b[h]
__global__ void k_init(const float* __restrict__ enc_b, float* __restrict__ zP0) {
  int idx = blockIdx.x * 256 + threadIdx.x;     // 65536
  int kk = idx & 3, h4 = (idx >> 8) & 63;
  zP0[idx] = enc_b[h4 * 4 + kk];
}

__global__ void k_bar0(unsigned int* bar) {
  bar[0] = 0u;  bar[32] = 0u;                   // cnt, gen (separate lines)
}

// ---------------------------------------------------------------------------
__device__ __forceinline__ void gbar(unsigned int* cnt, unsigned int* gen) {
  __syncthreads();
  if (threadIdx.x == 0) {
    __threadfence();                            // flush block's writes (agent)
    unsigned int g = __hip_atomic_load(gen, __ATOMIC_RELAXED, __HIP_MEMORY_SCOPE_AGENT);
    unsigned int a = __hip_atomic_fetch_add(cnt, 1u, __ATOMIC_ACQ_REL, __HIP_MEMORY_SCOPE_AGENT);
    if (a == NBLK - 1) {
      __hip_atomic_store(cnt, 0u, __ATOMIC_RELAXED, __HIP_MEMORY_SCOPE_AGENT);
      __hip_atomic_store(gen, g + 1u, __ATOMIC_RELEASE, __HIP_MEMORY_SCOPE_AGENT);
    } else {
      while (__hip_atomic_load(gen, __ATOMIC_ACQUIRE, __HIP_MEMORY_SCOPE_AGENT) == g)
        __builtin_amdgcn_s_sleep(2);
    }
    __threadfence();                            // invalidate stale cached lines
  }
  __syncthreads();
}

// ---------------------------------------------------------------------------
// Persistent kernel: 256 blocks (bq = blk&3 owns 64 b, hq = blk>>2 owns 4 h),
// 256 threads = 4 waves (kq = K-quarter). Runs all 254 substeps.
__global__ __launch_bounds__(256, 1)
void k_ode(char* __restrict__ wsb,
           const float* __restrict__ f_W1, const float* __restrict__ f_b1,
           const float* __restrict__ f_b2,
           const float* __restrict__ dec_W, const float* __restrict__ dec_b,
           float* __restrict__ out) {
  const int tid = threadIdx.x;
  const int lane = tid & 63, kq = tid >> 6;
  const int bq = blockIdx.x & 3, hq = blockIdx.x >> 2;
  const int gg = lane >> 4, c16 = lane & 15;

  float* dXr = (float*)(wsb + OFF_DXR);
  float* zP  = (float*)(wsb + OFF_ZP);
  unsigned short* hdnHiU = (unsigned short*)(wsb + OFF_HHI);
  unsigned short* hdnLoU = (unsigned short*)(wsb + OFF_HLO);
  unsigned int* bcnt = (unsigned int*)(wsb + OFF_BAR);
  unsigned int* bgen = bcnt + 32;

  // LDS: zsl4 (64KB) unioned with redB (3*64*84*4 = 64,512B); then statics.
  __shared__ __align__(16) char smem[65536 + 4096 + 3072 + 1024 + 384];
  float4* zsl4 = (float4*)smem;                        // [64 k4][64 b]
  float*  redB = (float*)smem;                         // [(j*64+lane)*84 + 4*(mt*4+nt)]
  float4* W1L4 = (float4*)(smem + 65536);              // [k][4 h]  (256)
  float (*redA)[64][4] = (float(*)[64][4])(smem + 69632);
  float4* decL4 = (float4*)(smem + 72704);             // [k4][4 kk] for y=hq
  float*  b2L   = (float*)(smem + 73728);              // 80 rows
  float*  b1L   = b2L + 80;                            // 4

  // ---- one-time LDS loads ----
  W1L4[tid] = *(const float4*)(f_W1 + tid * 256 + hq * 4);
  if (tid < 80) { int hl = tid / 20, c = tid - hl * 20;
                  b2L[tid] = (c < C_) ? f_b2[(hq * 4 + hl) * C_ + c] : 0.f; }
  if (tid < 4)  b1L[tid] = f_b1[hq * 4 + tid];
  if (hq < 16 && tid < 64)
    decL4[tid] = make_float4(dec_W[(4 * tid + 0) * 16 + hq], dec_W[(4 * tid + 1) * 16 + hq],
                             dec_W[(4 * tid + 2) * 16 + hq], dec_W[(4 * tid + 3) * 16 + hq]);
  float decbY = (hq < 16) ? dec_b[hq] : 0.f;

  // ---- persistent W2 A-fragments (hi/lo), this wave's K-quarter ----
  bf16x8 wHi[2][5], wLo[2][5];
  {
    const bf16x8* WH = (const bf16x8*)(wsb + OFF_W2H);
    const bf16x8* WL = (const bf16x8*)(wsb + OFF_W2L);
    #pragma unroll
    for (int ktl = 0; ktl < 2; ++ktl)
      #pragma unroll
      for (int mt = 0; mt < 5; ++mt) {
        int f = ((((hq * 4 + kq) * 2 + ktl) * 5 + mt) << 6) + lane;
        wHi[ktl][mt] = WH[f];
        wLo[ktl][mt] = WL[f];
      }
  }
  __syncthreads();

  for (int sub = 0; ; ++sub) {
    const float* zc = zP + (sub & 1) * 65536;
    float*       zn = zP + ((sub & 1) ^ 1) * 65536;

    // ---- stage this bq's z slab into LDS ----
    const float4* zsrc = (const float4*)zc + bq * 4096;
    #pragma unroll
    for (int j = 0; j < 16; ++j) zsl4[tid + j * 256] = zsrc[tid + j * 256];
    __syncthreads();

    // ---- decode out[sub/2] on even substeps (blocks hq<16, y=hq) ----
    bool deco = ((sub & 1) == 0) && (hq < 16);
    float accD = 0.f;
    if (deco) {
      #pragma unroll
      for (int i = 0; i < 16; ++i) {
        int k4 = kq * 16 + i;
        float4 a4 = zsl4[k4 * 64 + lane];
        float4 w4 = decL4[k4];
        accD = fmaf(a4.x, w4.x, accD); accD = fmaf(a4.y, w4.y, accD);
        accD = fmaf(a4.z, w4.z, accD); accD = fmaf(a4.w, w4.w, accD);
      }
      if (kq) redA[kq - 1][lane][0] = accD;
    }
    __syncthreads();
    if (deco && kq == 0) {
      accD += redA[0][lane][0] + redA[1][lane][0] + redA[2][lane][0];
      out[(sub >> 1) * 4096 + (bq * 64 + lane) * 16 + hq] = accD + decbY;
    }
    __syncthreads();
    if (sub == NSUB) break;

    // ---- phase A: hdn[64b][4h] = relu(z @ W1 + b1), fp32, k-split waves ----
    {
      float a0 = 0.f, a1 = 0.f, a2 = 0.f, a3 = 0.f;
      #pragma unroll
      for (int i = 0; i < 16; ++i) {
        int k4 = kq * 16 + i;
        float4 a4 = zsl4[k4 * 64 + lane];
        float4 w;
        w = W1L4[k4 * 4 + 0]; a0 = fmaf(a4.x, w.x, a0); a1 = fmaf(a4.x, w.y, a1); a2 = fmaf(a4.x, w.z, a2); a3 = fmaf(a4.x, w.w, a3);
        w = W1L4[k4 * 4 + 1]; a0 = fmaf(a4.y, w.x, a0); a1 = fmaf(a4.y, w.y, a1); a2 = fmaf(a4.y, w.z, a2); a3 = fmaf(a4.y, w.w, a3);
        w = W1L4[k4 * 4 + 2]; a0 = fmaf(a4.z, w.x, a0); a1 = fmaf(a4.z, w.y, a1); a2 = fmaf(a4.z, w.z, a2); a3 = fmaf(a4.z, w.w, a3);
        w = W1L4[k4 * 4 + 3]; a0 = fmaf(a4.w, w.x, a0); a1 = fmaf(a4.w, w.y, a1); a2 = fmaf(a4.w, w.z, a2); a3 = fmaf(a4.w, w.w, a3);
      }
      if (kq) { redA[kq - 1][lane][0] = a0; redA[kq - 1][lane][1] = a1;
                redA[kq - 1][lane][2] = a2; redA[kq - 1][lane][3] = a3; }
      __syncthreads();
      if (kq == 0) {
        float acc[4] = {a0, a1, a2, a3};
        #pragma unroll
        for (int hl = 0; hl < 4; ++hl) {
          float v = acc[hl] + redA[0][lane][hl] + redA[1][lane][hl] + redA[2][lane][hl];
          v = fmaxf(v + b1L[hl], 0.f);
          unsigned short hi, lo; bsplit(v, hi, lo);
          int h = hq * 4 + hl;
          int kt = h >> 5, p = h & 31;
          int fidx = ((kt * 4 + (lane >> 4)) * 64 + ((p >> 2) & 3) * 16 + (lane & 15)) * 8
                     + (p >> 4) * 4 + (p & 3);
          hdnHiU[bq * 16384 + fidx] = hi;
          hdnLoU[bq * 16384 + fidx] = lo;
        }
      }
    }
    gbar(bcnt, bgen);

    // ---- phase B: out[80 col][64 b] = W2slab^T @ hdn^T via MFMA (split bf16)
    {
      f32x4 acc[5][4];
      #pragma unroll
      for (int mt = 0; mt < 5; ++mt)
        #pragma unroll
        for (int nt = 0; nt < 4; ++nt) acc[mt][nt] = (f32x4){0.f, 0.f, 0.f, 0.f};

      const bf16x8* hH = (const bf16x8*)(wsb + OFF_HHI) + bq * 2048;
      const bf16x8* hL = (const bf16x8*)(wsb + OFF_HLO) + bq * 2048;
      #pragma unroll
      for (int ktl = 0; ktl < 2; ++ktl) {
        int kt = kq * 2 + ktl;
        bf16x8 bH[4], bL[4];
        #pragma unroll
        for (int nt = 0; nt < 4; ++nt) {
          int f = (kt * 4 + nt) * 64 + lane;
          bH[nt] = hH[f]; bL[nt] = hL[f];
        }
        #pragma unroll
        for (int mt = 0; mt < 5; ++mt)
          #pragma unroll
          for (int nt = 0; nt < 4; ++nt) {
            acc[mt][nt] = __builtin_amdgcn_mfma_f32_16x16x32_bf16(wHi[ktl][mt], bH[nt], acc[mt][nt], 0, 0, 0);
            acc[mt][nt] = __builtin_amdgcn_mfma_f32_16x16x32_bf16(wHi[ktl][mt], bL[nt], acc[mt][nt], 0, 0, 0);
            acc[mt][nt] = __builtin_amdgcn_mfma_f32_16x16x32_bf16(wLo[ktl][mt], bH[nt], acc[mt][nt], 0, 0, 0);
          }
      }

      // cross-wave K reduction (stride 84 floats to spread banks)
      if (kq) {
        float* r = redB + ((kq - 1) * 64 + lane) * 84;
        #pragma unroll
        for (int mt = 0; mt < 5; ++mt)
          #pragma unroll
          for (int nt = 0; nt < 4; ++nt)
            *(f32x4*)(r + (mt * 4 + nt) * 4) = acc[mt][nt];
      }
      __syncthreads();
      if (kq == 0) {
        #pragma unroll
        for (int j = 0; j < 3; ++j) {
          const float* r = redB + (j * 64 + lane) * 84;
          #pragma unroll
          for (int mt = 0; mt < 5; ++mt)
            #pragma unroll
            for (int nt = 0; nt < 4; ++nt)
              acc[mt][nt] += *(const f32x4*)(r + (mt * 4 + nt) * 4);
        }
        // epilogue: +b2, tanh, *dX, sum 17 c's per h, update z
        float ph[4][4] = {{0.f,0.f,0.f,0.f},{0.f,0.f,0.f,0.f},{0.f,0.f,0.f,0.f},{0.f,0.f,0.f,0.f}};
        #pragma unroll
        for (int mt = 0; mt < 5; ++mt) {
          int row0 = mt * 16 + 4 * gg;            // global col-row of reg 0
          float4 b2v = *(const float4*)&b2L[row0];
          int hmt = row0 / 20;
          int c0  = row0 - hmt * 20;
          #pragma unroll
          for (int nt = 0; nt < 4; ++nt) {
            int b_loc = nt * 16 + c16;
            float4 dxv = *(const float4*)(dXr + ((size_t)sub * 256 + bq * 64 + b_loc) * 20 + c0);
            f32x4 a = acc[mt][nt];
            float t0 = fast_tanh(a[0] + b2v.x);
            float t1 = fast_tanh(a[1] + b2v.y);
            float t2 = fast_tanh(a[2] + b2v.z);
            float t3 = fast_tanh(a[3] + b2v.w);
            float contrib = fmaf(t0, dxv.x, fmaf(t1, dxv.y, fmaf(t2, dxv.z, t3 * dxv.w)));
            #pragma unroll
            for (int h = 0; h < 4; ++h)
              ph[h][nt] += (hmt == h) ? contrib : 0.f;
          }
        }
        #pragma unroll
        for (int h = 0; h < 4; ++h)
          #pragma unroll
          for (int nt = 0; nt < 4; ++nt) {
            float v = ph[h][nt];
            v += __shfl_xor(v, 16);
            v += __shfl_xor(v, 32);
            ph[h][nt] = v;
          }
        #pragma unroll
        for (int nt = 0; nt < 4; ++nt) {
          float val = (gg == 0) ? ph[0][nt] : (gg == 1) ? ph[1][nt]
                    : (gg == 2) ? ph[2][nt] : ph[3][nt];
          int b_loc = nt * 16 + c16;
          int zi = bq * 16384 + hq * 256 + b_loc * 4 + gg;
          zn[zi] = zc[zi] + val;
        }
      }
    }
    gbar(bcnt, bgen);
  }
}

// ---------------------------------------------------------------------------
extern "C" void kernel_launch(void* const* d_in, const int* in_sizes, int n_in,
                              void* d_out, int out_size, void* d_ws, size_t ws_size,
                              hipStream_t stream) {
  const float* ts    = (const float*)d_in[0];
  const float* us    = (const float*)d_in[1];
  const float* enc_b = (const float*)d_in[5];
  const float* dec_W = (const float*)d_in[6];
  const float* dec_b = (const float*)d_in[7];
  const float* f_W1  = (const float*)d_in[8];
  const float* f_b1  = (const float*)d_in[9];
  const float* f_W2  = (const float*)d_in[10];
  const float* f_b2  = (const float*)d_in[11];
  float* out = (float*)d_out;
  char* wsb = (char*)d_ws;

  k_dx  <<<5080, 256, 0, stream>>>(ts, us, (float*)(wsb + OFF_DXR));
  k_w2f <<<10240, 256, 0, stream>>>(f_W2, (unsigned short*)(wsb + OFF_W2H),
                                    (unsigned short*)(wsb + OFF_W2L));
  k_init<<<256, 256, 0, stream>>>(enc_b, (float*)(wsb + OFF_ZP));
  k_bar0<<<1, 64, 0, stream>>>((unsigned int*)(wsb + OFF_BAR));

  k_ode<<<NBLK, 256, 0, stream>>>(wsb, f_W1, f_b1, f_b2, dec_W, dec_b, out);
}

// Round 5
// 3655.630 us; speedup vs baseline: 3.9564x; 3.9564x over previous
//
#include <hip/hip_runtime.h>
#include <hip/hip_bf16.h>
#include <cmath>

// L=128, B=256, H=256, C=17, Y=16, N_SUB=2
#define L_   128
#define B_   256
#define H_   256
#define C_   17
#define Y_   16
#define NSUB 254
#define NBLK 256

typedef short bf16x8 __attribute__((ext_vector_type(8)));
typedef float f32x4  __attribute__((ext_vector_type(4)));

// ---- workspace byte offsets -------------------------------------------------
// dXr  [254][256 b][20 c-pad] f32                     5,201,920
// zP   [4 bq][64 h4][64 b][4 kk] f32 (single buffer)    262,144
// hdnG hi/lo planes, frag-ordered bf16, per bq 32KB     131,072 each
// W2F  hi/lo planes, frag-ordered bf16                 5,242,880 each
// barriers: 4 monotonic counters, 512B apart
#define OFF_DXR  0u
#define OFF_ZP   5201920u
#define OFF_HHI  5726208u
#define OFF_HLO  5857280u
#define OFF_W2H  5988352u
#define OFF_W2L  11231232u
#define OFF_BAR  16474112u

__device__ __forceinline__ float fast_tanh(float x) {
  float e = __expf(2.0f * x);
  return 1.0f - __fdividef(2.0f, e + 1.0f);
}

__device__ __forceinline__ void bsplit(float x, unsigned short& hi, unsigned short& lo) {
  __hip_bfloat16 h = __float2bfloat16(x);
  float hf = __bfloat162float(h);
  __hip_bfloat16 l = __float2bfloat16(x - hf);
  hi = *(unsigned short*)&h;
  lo = *(unsigned short*)&l;
}

// ---- coherent (L1/L2-bypass) access helpers: data visible via L3 ------------
__device__ __forceinline__ void ldx8p_coh(f32x4 r[8],
    const void* p0, const void* p1, const void* p2, const void* p3,
    const void* p4, const void* p5, const void* p6, const void* p7) {
  asm volatile(
    "global_load_dwordx4 %0, %8, off sc0 sc1\n\t"
    "global_load_dwordx4 %1, %9, off sc0 sc1\n\t"
    "global_load_dwordx4 %2, %10, off sc0 sc1\n\t"
    "global_load_dwordx4 %3, %11, off sc0 sc1\n\t"
    "global_load_dwordx4 %4, %12, off sc0 sc1\n\t"
    "global_load_dwordx4 %5, %13, off sc0 sc1\n\t"
    "global_load_dwordx4 %6, %14, off sc0 sc1\n\t"
    "global_load_dwordx4 %7, %15, off sc0 sc1\n\t"
    "s_waitcnt vmcnt(0)"
    : "=&v"(r[0]), "=&v"(r[1]), "=&v"(r[2]), "=&v"(r[3]),
      "=&v"(r[4]), "=&v"(r[5]), "=&v"(r[6]), "=&v"(r[7])
    : "v"(p0), "v"(p1), "v"(p2), "v"(p3), "v"(p4), "v"(p5), "v"(p6), "v"(p7)
    : "memory");
}

__device__ __forceinline__ void st_coh_f32(float* p, float v) {
  asm volatile("global_store_dword %0, %1, off sc0 sc1" :: "v"(p), "v"(v) : "memory");
}

__device__ __forceinline__ void st_coh_u16(unsigned short* p, unsigned int v) {
  asm volatile("global_store_short %0, %1, off sc0 sc1" :: "v"(p), "v"(v) : "memory");
}

// ---------------------------------------------------------------------------
// dXr[sub][b][c(20 pad)] = dX * (h/2)   (c>=17 -> 0)
__global__ void k_dx(const float* __restrict__ ts, const float* __restrict__ us,
                     float* __restrict__ dXr) {
  int idx = blockIdx.x * 256 + threadIdx.x;     // 254*256*20 = 1,300,480 exact
  int c   = idx % 20;
  int t2  = idx / 20;
  int b   = t2 & 255;
  int sub = t2 >> 8;
  if (c >= C_) { dXr[idx] = 0.f; return; }
  int s = sub >> 1, j = sub & 1;
  float t_s = ts[s * B_], t_n = ts[(s + 1) * B_];
  float h = t_n - t_s;
  float xi, xn;
  if (c == 0) { xi = ts[s * B_ + b]; xn = ts[(s + 1) * B_ + b]; }
  else {
    xi = us[(size_t)s       * 4096 + b * 16 + (c - 1)];
    xn = us[(size_t)(s + 1) * 4096 + b * 16 + (c - 1)];
  }
  float mn = (xn - xi) / h;
  float mi;
  if (s == 0) mi = mn;
  else {
    float hp = t_s - ts[(s - 1) * B_];
    float xp = (c == 0) ? ts[(s - 1) * B_ + b]
                        : us[(size_t)(s - 1) * 4096 + b * 16 + (c - 1)];
    mi = (xi - xp) / hp;
  }
  float c2 = 3.f * (xn - xi) / (h * h) - (2.f * mi + mn) / h;
  float c3 = 2.f * (xi - xn) / (h * h * h) + (mi + mn) / (h * h);
  float u  = j ? 0.5f * h : 0.f;
  float dX = mi + 2.f * c2 * u + 3.f * c3 * u * u;
  dXr[idx] = dX * 0.5f * h;
}

// ---------------------------------------------------------------------------
// Build W2 A-fragments (transposed GEMM: A[m=col(80)][k=256]), hi/lo bf16.
__global__ void k_w2f(const float* __restrict__ W2,
                      unsigned short* __restrict__ W2H,
                      unsigned short* __restrict__ W2L) {
  int idx = blockIdx.x * 256 + threadIdx.x;     // 2,621,440 exact
  int e = idx & 7, t = idx >> 3;
  int lane = t & 63; t >>= 6;
  int mt = t % 5;  t /= 5;
  int kt = t & 1;  t >>= 1;
  int kq = t & 3;  t >>= 2;
  int hq = t;                                   // 0..63
  int col = mt * 16 + (lane & 15);
  int hl = col / 20, c = col - hl * 20;
  int k = kq * 64 + kt * 32 + 4 * (lane >> 4) + (e & 3) + 16 * (e >> 2);
  float v = (c < C_) ? W2[(size_t)k * (H_ * C_) + (hq * 4 + hl) * C_ + c] : 0.f;
  unsigned short hi, lo;
  bsplit(v, hi, lo);
  W2H[idx] = hi;
  W2L[idx] = lo;
}

// zP init: layout [bq][h4][b64][kk], z0[b][h] = enc_b[h]
__global__ void k_init(const float* __restrict__ enc_b, float* __restrict__ zP0) {
  int idx = blockIdx.x * 256 + threadIdx.x;     // 65536
  int kk = idx & 3, h4 = (idx >> 8) & 63;
  zP0[idx] = enc_b[h4 * 4 + kk];
}

__global__ void k_bar0(unsigned int* bar) {
  if (threadIdx.x < 4) bar[threadIdx.x * 128] = 0u;   // 4 group counters, 512B apart
}

// ---------------------------------------------------------------------------
// Fence-free group barrier: monotonic counter, RELAXED agent atomics (sc1 ops
// at the coherent point; NO L2 writeback/invalidate). vmcnt(0) drains this
// wave's sc0sc1 data stores before arrival.
__device__ __forceinline__ void gbar(unsigned int* cnt, unsigned int target) {
  __syncthreads();
  if (threadIdx.x == 0) {
    asm volatile("s_waitcnt vmcnt(0)" ::: "memory");
    __hip_atomic_fetch_add(cnt, 1u, __ATOMIC_RELAXED, __HIP_MEMORY_SCOPE_AGENT);
    unsigned int guard = 0;
    while (__hip_atomic_load(cnt, __ATOMIC_RELAXED, __HIP_MEMORY_SCOPE_AGENT) < target) {
      __builtin_amdgcn_s_sleep(4);
      if (++guard > (1u << 20)) break;          // failsafe vs hard hang
    }
  }
  __syncthreads();
}

// ---------------------------------------------------------------------------
// Persistent kernel: 256 blocks (bq = blk&3 owns 64 b, hq = blk>>2 owns 4 h),
// 4 waves (kq = K-quarter). All cross-block deps stay within the bq group.
__global__ __launch_bounds__(256, 1)
void k_ode(char* __restrict__ wsb,
           const float* __restrict__ f_W1, const float* __restrict__ f_b1,
           const float* __restrict__ f_b2,
           const float* __restrict__ dec_W, const float* __restrict__ dec_b,
           float* __restrict__ out) {
  const int tid = threadIdx.x;
  const int lane = tid & 63, kq = tid >> 6;
  const int bq = blockIdx.x & 3, hq = blockIdx.x >> 2;
  const int gg = lane >> 4, c16 = lane & 15;

  float* dXr = (float*)(wsb + OFF_DXR);
  float* zP  = (float*)(wsb + OFF_ZP);
  unsigned short* hdnHiU = (unsigned short*)(wsb + OFF_HHI);
  unsigned short* hdnLoU = (unsigned short*)(wsb + OFF_HLO);
  unsigned int* mycnt = (unsigned int*)(wsb + OFF_BAR) + (size_t)bq * 128;
  unsigned int bt = 64;                          // barrier target (64 blocks/group)

  // LDS: zsl4 (64KB) unioned with redB (64,512B); then statics.
  __shared__ __align__(16) char smem[65536 + 4096 + 3072 + 1024 + 384];
  f32x4*  zsl4 = (f32x4*)smem;                        // [64 k4][64 b]
  float*  redB = (float*)smem;                        // [(j*64+lane)*84 + ...]
  float4* W1L4 = (float4*)(smem + 65536);             // [k][4 h]
  float (*redA)[64][4] = (float(*)[64][4])(smem + 69632);
  float4* decL4 = (float4*)(smem + 72704);            // [k4][4 kk] for y=hq
  float*  b2L   = (float*)(smem + 73728);             // 80 rows
  float*  b1L   = b2L + 80;                           // 4

  // ---- one-time LDS loads ----
  W1L4[tid] = *(const float4*)(f_W1 + tid * 256 + hq * 4);
  if (tid < 80) { int hl = tid / 20, c = tid - hl * 20;
                  b2L[tid] = (c < C_) ? f_b2[(hq * 4 + hl) * C_ + c] : 0.f; }
  if (tid < 4)  b1L[tid] = f_b1[hq * 4 + tid];
  if (hq < 16 && tid < 64)
    decL4[tid] = make_float4(dec_W[(4 * tid + 0) * 16 + hq], dec_W[(4 * tid + 1) * 16 + hq],
                             dec_W[(4 * tid + 2) * 16 + hq], dec_W[(4 * tid + 3) * 16 + hq]);
  float decbY = (hq < 16) ? dec_b[hq] : 0.f;

  // ---- persistent W2 A-fragments (hi/lo), this wave's K-quarter ----
  bf16x8 wHi[2][5], wLo[2][5];
  {
    const bf16x8* WH = (const bf16x8*)(wsb + OFF_W2H);
    const bf16x8* WL = (const bf16x8*)(wsb + OFF_W2L);
    #pragma unroll
    for (int ktl = 0; ktl < 2; ++ktl)
      #pragma unroll
      for (int mt = 0; mt < 5; ++mt) {
        int f = ((((hq * 4 + kq) * 2 + ktl) * 5 + mt) << 6) + lane;
        wHi[ktl][mt] = WH[f];
        wLo[ktl][mt] = WL[f];
      }
  }

  // ---- block-private z accumulator (this block's 4h x its lane's b's) ----
  float zreg[4];
  #pragma unroll
  for (int nt = 0; nt < 4; ++nt)
    zreg[nt] = zP[bq * 16384 + hq * 256 + (nt * 16 + c16) * 4 + gg];
  __syncthreads();

  for (int sub = 0; ; ++sub) {
    // ---- stage this bq's z slab into LDS (coherent bypass loads) ----
    {
      const f32x4* zsrc = (const f32x4*)zP + bq * 4096 + tid;
      f32x4 zr[8];
      ldx8p_coh(zr, zsrc, zsrc + 256, zsrc + 512, zsrc + 768,
                    zsrc + 1024, zsrc + 1280, zsrc + 1536, zsrc + 1792);
      #pragma unroll
      for (int j = 0; j < 8; ++j) zsl4[tid + j * 256] = zr[j];
      ldx8p_coh(zr, zsrc + 2048, zsrc + 2304, zsrc + 2560, zsrc + 2816,
                    zsrc + 3072, zsrc + 3328, zsrc + 3584, zsrc + 3840);
      #pragma unroll
      for (int j = 0; j < 8; ++j) zsl4[tid + (8 + j) * 256] = zr[j];
    }
    __syncthreads();

    // ---- decode out[sub/2] on even substeps (blocks hq<16, y=hq) ----
    bool deco = ((sub & 1) == 0) && (hq < 16);
    float accD = 0.f;
    if (deco) {
      #pragma unroll
      for (int i = 0; i < 16; ++i) {
        int k4 = kq * 16 + i;
        f32x4 a4 = zsl4[k4 * 64 + lane];
        float4 w4 = decL4[k4];
        accD = fmaf(a4[0], w4.x, accD); accD = fmaf(a4[1], w4.y, accD);
        accD = fmaf(a4[2], w4.z, accD); accD = fmaf(a4[3], w4.w, accD);
      }
      if (kq) redA[kq - 1][lane][0] = accD;
    }
    __syncthreads();
    if (deco && kq == 0) {
      accD += redA[0][lane][0] + redA[1][lane][0] + redA[2][lane][0];
      out[(sub >> 1) * 4096 + (bq * 64 + lane) * 16 + hq] = accD + decbY;
    }
    __syncthreads();
    if (sub == NSUB) break;

    // ---- phase A: hdn[64b][4h] = relu(z @ W1 + b1), fp32, k-split waves ----
    {
      float a0 = 0.f, a1 = 0.f, a2 = 0.f, a3 = 0.f;
      #pragma unroll
      for (int i = 0; i < 16; ++i) {
        int k4 = kq * 16 + i;
        f32x4 a4 = zsl4[k4 * 64 + lane];
        float4 w;
        w = W1L4[k4 * 4 + 0]; a0 = fmaf(a4[0], w.x, a0); a1 = fmaf(a4[0], w.y, a1); a2 = fmaf(a4[0], w.z, a2); a3 = fmaf(a4[0], w.w, a3);
        w = W1L4[k4 * 4 + 1]; a0 = fmaf(a4[1], w.x, a0); a1 = fmaf(a4[1], w.y, a1); a2 = fmaf(a4[1], w.z, a2); a3 = fmaf(a4[1], w.w, a3);
        w = W1L4[k4 * 4 + 2]; a0 = fmaf(a4[2], w.x, a0); a1 = fmaf(a4[2], w.y, a1); a2 = fmaf(a4[2], w.z, a2); a3 = fmaf(a4[2], w.w, a3);
        w = W1L4[k4 * 4 + 3]; a0 = fmaf(a4[3], w.x, a0); a1 = fmaf(a4[3], w.y, a1); a2 = fmaf(a4[3], w.z, a2); a3 = fmaf(a4[3], w.w, a3);
      }
      if (kq) { redA[kq - 1][lane][0] = a0; redA[kq - 1][lane][1] = a1;
                redA[kq - 1][lane][2] = a2; redA[kq - 1][lane][3] = a3; }
      __syncthreads();
      if (kq == 0) {
        float acc[4] = {a0, a1, a2, a3};
        #pragma unroll
        for (int hl = 0; hl < 4; ++hl) {
          float v = acc[hl] + redA[0][lane][hl] + redA[1][lane][hl] + redA[2][lane][hl];
          v = fmaxf(v + b1L[hl], 0.f);
          unsigned short hi, lo; bsplit(v, hi, lo);
          int h = hq * 4 + hl;
          int kt = h >> 5, p = h & 31;
          int fidx = ((kt * 4 + (lane >> 4)) * 64 + ((p >> 2) & 3) * 16 + (lane & 15)) * 8
                     + (p >> 4) * 4 + (p & 3);
          st_coh_u16(hdnHiU + bq * 16384 + fidx, hi);
          st_coh_u16(hdnLoU + bq * 16384 + fidx, lo);
        }
      }
    }
    gbar(mycnt, bt); bt += 64;

    // ---- phase B: out[80 col][64 b] = W2slab^T @ hdn^T via MFMA (split bf16)
    {
      f32x4 acc[5][4];
      #pragma unroll
      for (int mt = 0; mt < 5; ++mt)
        #pragma unroll
        for (int nt = 0; nt < 4; ++nt) acc[mt][nt] = (f32x4){0.f, 0.f, 0.f, 0.f};

      const f32x4* hH = (const f32x4*)(wsb + OFF_HHI) + bq * 2048;
      const f32x4* hL = (const f32x4*)(wsb + OFF_HLO) + bq * 2048;
      #pragma unroll
      for (int ktl = 0; ktl < 2; ++ktl) {
        int kt = kq * 2 + ktl;
        int f = (kt * 4) * 64 + lane;
        f32x4 hr[8];
        ldx8p_coh(hr, hH + f, hH + f + 64, hH + f + 128, hH + f + 192,
                      hL + f, hL + f + 64, hL + f + 128, hL + f + 192);
        bf16x8 bH[4], bL[4];
        #pragma unroll
        for (int nt = 0; nt < 4; ++nt) {
          bH[nt] = __builtin_bit_cast(bf16x8, hr[nt]);
          bL[nt] = __builtin_bit_cast(bf16x8, hr[4 + nt]);
        }
        #pragma unroll
        for (int mt = 0; mt < 5; ++mt)
          #pragma unroll
          for (int nt = 0; nt < 4; ++nt) {
            acc[mt][nt] = __builtin_amdgcn_mfma_f32_16x16x32_bf16(wHi[ktl][mt], bH[nt], acc[mt][nt], 0, 0, 0);
            acc[mt][nt] = __builtin_amdgcn_mfma_f32_16x16x32_bf16(wHi[ktl][mt], bL[nt], acc[mt][nt], 0, 0, 0);
            acc[mt][nt] = __builtin_amdgcn_mfma_f32_16x16x32_bf16(wLo[ktl][mt], bH[nt], acc[mt][nt], 0, 0, 0);
          }
      }

      // cross-wave K reduction (stride 84 floats to spread banks)
      if (kq) {
        float* r = redB + ((kq - 1) * 64 + lane) * 84;
        #pragma unroll
        for (int mt = 0; mt < 5; ++mt)
          #pragma unroll
          for (int nt = 0; nt < 4; ++nt)
            *(f32x4*)(r + (mt * 4 + nt) * 4) = acc[mt][nt];
      }
      __syncthreads();
      if (kq == 0) {
        #pragma unroll
        for (int j = 0; j < 3; ++j) {
          const float* r = redB + (j * 64 + lane) * 84;
          #pragma unroll
          for (int mt = 0; mt < 5; ++mt)
            #pragma unroll
            for (int nt = 0; nt < 4; ++nt)
              acc[mt][nt] += *(const f32x4*)(r + (mt * 4 + nt) * 4);
        }
        // epilogue: +b2, tanh, *dX, sum 17 c's per h, update z
        float ph[4][4] = {{0.f,0.f,0.f,0.f},{0.f,0.f,0.f,0.f},{0.f,0.f,0.f,0.f},{0.f,0.f,0.f,0.f}};
        #pragma unroll
        for (int mt = 0; mt < 5; ++mt) {
          int row0 = mt * 16 + 4 * gg;            // global col-row of reg 0
          float4 b2v = *(const float4*)&b2L[row0];
          int hmt = row0 / 20;
          int c0  = row0 - hmt * 20;
          #pragma unroll
          for (int nt = 0; nt < 4; ++nt) {
            int b_loc = nt * 16 + c16;
            float4 dxv = *(const float4*)(dXr + ((size_t)sub * 256 + bq * 64 + b_loc) * 20 + c0);
            f32x4 a = acc[mt][nt];
            float t0 = fast_tanh(a[0] + b2v.x);
            float t1 = fast_tanh(a[1] + b2v.y);
            float t2 = fast_tanh(a[2] + b2v.z);
            float t3 = fast_tanh(a[3] + b2v.w);
            float contrib = fmaf(t0, dxv.x, fmaf(t1, dxv.y, fmaf(t2, dxv.z, t3 * dxv.w)));
            #pragma unroll
            for (int h = 0; h < 4; ++h)
              ph[h][nt] += (hmt == h) ? contrib : 0.f;
          }
        }
        #pragma unroll
        for (int h = 0; h < 4; ++h)
          #pragma unroll
          for (int nt = 0; nt < 4; ++nt) {
            float v = ph[h][nt];
            v += __shfl_xor(v, 16);
            v += __shfl_xor(v, 32);
            ph[h][nt] = v;
          }
        #pragma unroll
        for (int nt = 0; nt < 4; ++nt) {
          float val = (gg == 0) ? ph[0][nt] : (gg == 1) ? ph[1][nt]
                    : (gg == 2) ? ph[2][nt] : ph[3][nt];
          zreg[nt] += val;
          int zi = bq * 16384 + hq * 256 + (nt * 16 + c16) * 4 + gg;
          st_coh_f32(zP + zi, zreg[nt]);
        }
      }
    }
    gbar(mycnt, bt); bt += 64;
  }
}

// ---------------------------------------------------------------------------
extern "C" void kernel_launch(void* const* d_in, const int* in_sizes, int n_in,
                              void* d_out, int out_size, void* d_ws, size_t ws_size,
                              hipStream_t stream) {
  const float* ts    = (const float*)d_in[0];
  const float* us    = (const float*)d_in[1];
  const float* enc_b = (const float*)d_in[5];
  const float* dec_W = (const float*)d_in[6];
  const float* dec_b = (const float*)d_in[7];
  const float* f_W1  = (const float*)d_in[8];
  const float* f_b1  = (const float*)d_in[9];
  const float* f_W2  = (const float*)d_in[10];
  const float* f_b2  = (const float*)d_in[11];
  float* out = (float*)d_out;
  char* wsb = (char*)d_ws;

  k_dx  <<<5080, 256, 0, stream>>>(ts, us, (float*)(wsb + OFF_DXR));
  k_w2f <<<10240, 256, 0, stream>>>(f_W2, (unsigned short*)(wsb + OFF_W2H),
                                    (unsigned short*)(wsb + OFF_W2L));
  k_init<<<256, 256, 0, stream>>>(enc_b, (float*)(wsb + OFF_ZP));
  k_bar0<<<1, 64, 0, stream>>>((unsigned int*)(wsb + OFF_BAR));

  k_ode<<<NBLK, 256, 0, stream>>>(wsb, f_W1, f_b1, f_b2, dec_W, dec_b, out);
}